// Round 6
// baseline (12.448 us; speedup 1.0000x reference)
//
#include <hip/hip_runtime.h>
#include <hip/hip_bf16.h>

#define BT_DEPTH 20
#define BT_NDIMS 128

// R2 structure (best measured: 9.34 us), with 32-bit address math on the
// critical idx->load path. One block, 4 waves. Wave w owns levels
// l = w, w+4, ... (6 for wave 0, 5 for waves 1..3). No LDS staging of x:
// each lane loads its own float2 of the leaf row, so all loads issue in one
// latency round-trip after the index loads resolve. Each wave folds its
// levels into a partial product of (1+exp(-z)); one barrier; thread 0
// combines with a single reciprocal.
__global__ __launch_bounds__(256) void BinaryTree_18734647345500_kernel(
    const float* __restrict__ W,
    const int* __restrict__ v_j_idx,
    const int* __restrict__ u_k_idx,
    float* __restrict__ out)
{
    __shared__ float pp[4];

    const int tid  = threadIdx.x;
    const int wave = tid >> 6;
    const int lane = tid & 63;

    const int v = v_j_idx[0];
    const int u = u_k_idx[0];

    // 32-bit flat element offsets: max node 2^21, *128 -> <2^28. Safe.
    const unsigned leafOff = ((unsigned)v + ((1u << BT_DEPTH) - 1u)) * BT_NDIMS
                             + (unsigned)(lane * 2);
    const unsigned t = (unsigned)u + (1u << BT_DEPTH);

    // This lane's 2 dims of x (no LDS, no barrier).
    const float2 xv = *(const float2*)(W + leafOff);

    // Issue all path-row loads back-to-back (independent).
    float z[6];
    #pragma unroll
    for (int i = 0; i < 6; ++i) {
        const int l = wave + 4 * i;
        // waves 1..3, i==5 -> l>20: clamp shift (loads leaf row, discarded).
        const int shift = (l <= BT_DEPTH) ? (BT_DEPTH - l) : 0;
        const unsigned rowOff = ((t >> shift) - 1u) * BT_NDIMS + (unsigned)(lane * 2);
        const float2 rv = *(const float2*)(W + rowOff);
        z[i] = rv.x * xv.x + rv.y * xv.y;
    }

    // 64-lane butterfly reduce per level (6 independent chains -> ILP-hidden).
    #pragma unroll
    for (int i = 0; i < 6; ++i) {
        float s = z[i];
        s += __shfl_xor(s, 32, 64);
        s += __shfl_xor(s, 16, 64);
        s += __shfl_xor(s,  8, 64);
        s += __shfl_xor(s,  4, 64);
        s += __shfl_xor(s,  2, 64);
        s += __shfl_xor(s,  1, 64);
        z[i] = s;
    }

    if (lane == 0) {
        const int nlev = (wave == 0) ? 6 : 5;
        float q = 1.0f;
        #pragma unroll
        for (int i = 0; i < 6; ++i) {
            if (i < nlev) q *= 1.0f + __expf(-z[i]);
        }
        pp[wave] = q;
    }
    __syncthreads();

    if (tid == 0) {
        out[0] = 1.0f / (pp[0] * pp[1] * pp[2] * pp[3]);
    }
}

extern "C" void kernel_launch(void* const* d_in, const int* in_sizes, int n_in,
                              void* d_out, int out_size, void* d_ws, size_t ws_size,
                              hipStream_t stream) {
    const float* W   = (const float*)d_in[0];
    const int*   vj  = (const int*)d_in[1];
    const int*   uk  = (const int*)d_in[2];
    float*       out = (float*)d_out;

    hipLaunchKernelGGL(BinaryTree_18734647345500_kernel,
                       dim3(1), dim3(256), 0, stream,
                       W, vj, uk, out);
}